// Round 4
// baseline (1246.819 us; speedup 1.0000x reference)
//
#include <hip/hip_runtime.h>
#include <hip/hip_bf16.h>

#define NN      2048
#define NSTEPS  2047
#define NPAIRS  1024
#define MROWS   8192

typedef __attribute__((ext_vector_type(8))) __bf16 bf16x8;
typedef __attribute__((ext_vector_type(4))) float  f32x4;
typedef __attribute__((ext_vector_type(2))) float  f32x2;

__device__ __forceinline__ unsigned short f2bf(float f) {
  unsigned int u = __float_as_uint(f);
  u += 0x7fffu + ((u >> 16) & 1u);   // RNE
  return (unsigned short)(u >> 16);
}

__device__ __forceinline__ void gload_lds16(const void* g, void* l) {
  __builtin_amdgcn_global_load_lds((const __attribute__((address_space(1))) void*)g,
                                   (__attribute__((address_space(3))) void*)l, 16, 0, 0);
}

// ---- kernel 1: angles -> (cos,sin) table, layout cs[step][pair] (8 KB/step slice)
__global__ __launch_bounds__(256) void prep_kernel(
    const float* __restrict__ angles, float2* __restrict__ cs) {
  int idx = blockIdx.x * 256 + threadIdx.x;
  if (idx >= NSTEPS * NPAIRS) return;
  float s, c;
  sincosf(angles[idx], &s, &c);
  cs[idx] = make_float2(c, s);
}

// ---- kernel 2: x fp32 -> bf16 (vectorized)
__global__ __launch_bounds__(256) void cvt_kernel(
    const float4* __restrict__ x, ushort4* __restrict__ xb, int n4) {
  int idx = blockIdx.x * 256 + threadIdx.x;
  if (idx >= n4) return;
  float4 v = x[idx];
  ushort4 o;
  o.x = f2bf(v.x); o.y = f2bf(v.y); o.z = f2bf(v.z); o.w = f2bf(v.w);
  xb[idx] = o;
}

// ---- kernel 3: register-systolic build of U (position space, static pairing).
// WG = 4 waves (q = pair-quarter 0..3), owns 4 rows (f32x2 a = rows 0-1, b = rows 2-3).
// Lane of wave q owns pairs 256q+4l+e (e=0..3); F elem at pos p, S elem at pos 2047-p.
// Per step: rotate (lane-local), conveyor-shift (intra-wave shfl + inter-wave LDS exch).
// cs slices quad-buffered in LDS, staged 3 ahead with counted vmcnt(4) + raw s_barrier
// so staging loads stay in flight across barriers (T3/T4 pattern).
__global__ __launch_bounds__(256, 2) void build_kernel(
    const char* __restrict__ csb, unsigned short* __restrict__ Ub) {
  __shared__ __align__(16) char lds_cs[4][8192];
  __shared__ float4 exch[2][2][4];   // [parity][0=F fwd,1=S bwd][slot]

  const int tid  = threadIdx.x;
  const int lane = tid & 63;
  const int q    = tid >> 6;              // pair-quarter
  const int r0   = blockIdx.x * 4;        // rows r0..r0+3
  const bool l0 = (lane == 0), l63 = (lane == 63);
  const bool q0 = (q == 0), q3 = (q == 3);

  // state: elem e <-> pair p = 256q + 4*lane + e; reg at step T: F:(e-T)&3, S:(e+T)&3
  f32x2 FFa[4], FFb[4], SSa[4], SSb[4];
#pragma unroll
  for (int e = 0; e < 4; ++e) {
    const int p = 256 * q + 4 * lane + e;
    FFa[e] = (f32x2){(p == r0) ? 1.f : 0.f, (p == r0 + 1) ? 1.f : 0.f};
    FFb[e] = (f32x2){(p == r0 + 2) ? 1.f : 0.f, (p == r0 + 3) ? 1.f : 0.f};
    SSa[e] = (f32x2){((2047 - p) == r0) ? 1.f : 0.f, ((2047 - p) == r0 + 1) ? 1.f : 0.f};
    SSb[e] = (f32x2){((2047 - p) == r0 + 2) ? 1.f : 0.f, ((2047 - p) == r0 + 3) ? 1.f : 0.f};
  }

  // swizzled cv read offsets (2 x float4 = 32B per lane per step)
  const unsigned swz = 16u * (((unsigned)lane >> 2) & 7u);
  const unsigned aoff0 = (2048u * q + 32u * (unsigned)lane) ^ swz;
  const unsigned aoff1 = (2048u * q + 32u * (unsigned)lane + 16u) ^ swz;

  // staging: wave q stages 1KB blocks {2q, 2q+1}; linear LDS dest + pre-swizzled src
  const unsigned sl = 16u * ((unsigned)lane ^ ((unsigned)lane >> 3));
  const char* gp0 = csb + 2048 * q + sl;
  const char* gp1 = gp0 + 1024;

  // prologue: stage slices 0,1,2 into bufs 0,1,2
#pragma unroll
  for (int s = 0; s < 3; ++s) {
    gload_lds16(gp0, &lds_cs[s][2048 * q]);
    gload_lds16(gp1, &lds_cs[s][2048 * q + 1024]);
    gp0 += 8192; gp1 += 8192;
  }
  asm volatile("s_waitcnt vmcnt(4)" ::: "memory");   // slice 0 landed (1,2 in flight)
  __builtin_amdgcn_s_barrier();
  __builtin_amdgcn_sched_barrier(0);

#define ROT1(E, CC, SV) { \
    const int rF = ((E) - (PHI)) & 3, rS = ((E) + (PHI)) & 3; \
    const f32x2 c2 = {CC, CC}, s2 = {SV, SV}; \
    const f32x2 viA = FFa[rF], vjA = SSa[rS]; \
    FFa[rF] = c2 * viA + s2 * vjA; \
    SSa[rS] = c2 * vjA - s2 * viA; \
    const f32x2 viB = FFb[rF], vjB = SSb[rS]; \
    FFb[rF] = c2 * viB + s2 * vjB; \
    SSb[rS] = c2 * vjB - s2 * viB; }

#define STEP(PHI_) { \
    const int PHI = (PHI_); \
    const int PAR = PHI & 1; \
    const int pF = (3 - PHI) & 3, pT = (4 - PHI) & 3; \
    const float4 cv0 = *(const float4*)&lds_cs[PHI][aoff0]; \
    const float4 cv1 = *(const float4*)&lds_cs[PHI][aoff1]; \
    ROT1(0, cv0.x, cv0.y) ROT1(1, cv0.z, cv0.w) \
    ROT1(2, cv1.x, cv1.y) ROT1(3, cv1.z, cv1.w) \
    const f32x2 FoA = FFa[pF], FoB = FFb[pF]; \
    const f32x2 SoA = SSa[PHI], SoB = SSb[PHI]; \
    const f32x2 StA = FFa[pT], StB = FFb[pT]; \
    f32x2 fiA, fiB, sdA, sdB; \
    fiA.x = __shfl_up(FoA.x, 1);   fiA.y = __shfl_up(FoA.y, 1); \
    fiB.x = __shfl_up(FoB.x, 1);   fiB.y = __shfl_up(FoB.y, 1); \
    sdA.x = __shfl_down(SoA.x, 1); sdA.y = __shfl_down(SoA.y, 1); \
    sdB.x = __shfl_down(SoB.x, 1); sdB.y = __shfl_down(SoB.y, 1); \
    if (!q3 && l63) exch[PAR][0][q]     = make_float4(FoA.x, FoA.y, FoB.x, FoB.y); \
    if (!q0 && l0)  exch[PAR][1][q - 1] = make_float4(SoA.x, SoA.y, SoB.x, SoB.y); \
    gload_lds16(gp0, &lds_cs[(PHI + 3) & 3][2048 * q]); \
    gload_lds16(gp1, &lds_cs[(PHI + 3) & 3][2048 * q + 1024]); \
    gp0 += 8192; gp1 += 8192; \
    asm volatile("s_waitcnt vmcnt(4) lgkmcnt(0)" ::: "memory"); \
    __builtin_amdgcn_s_barrier(); \
    __builtin_amdgcn_sched_barrier(0); \
    float4 exF = make_float4(0.f, 0.f, 0.f, 0.f), exS = exF; \
    if (!q0 && l0)  exF = exch[PAR][0][q - 1]; \
    if (!q3 && l63) exS = exch[PAR][1][q]; \
    FFa[pF]  = l0  ? (q0 ? StA : (f32x2){exF.x, exF.y}) : fiA; \
    FFb[pF]  = l0  ? (q0 ? StB : (f32x2){exF.z, exF.w}) : fiB; \
    SSa[PHI] = l63 ? (q3 ? FoA : (f32x2){exS.x, exS.y}) : sdA; \
    SSb[PHI] = l63 ? (q3 ? FoB : (f32x2){exS.z, exS.w}) : sdB; \
    if (q0) { FFa[pT] = l0 ? SoA : FFa[pT]; FFb[pT] = l0 ? SoB : FFb[pT]; } \
  }

#pragma unroll 1
  for (int it = 0; it < 511; ++it) {
    STEP(0) STEP(1) STEP(2) STEP(3)
  }
  // tail: t = 2044, 2045, 2046 (stages pad slices 2047-2049, never read)
  STEP(0) STEP(1) STEP(2)

  // Readout at T=2047 (2047-cycle closed; 2047 mod 4 = 3):
  // F elem e in reg (e+1)&3, col 256q+4l+e; S elem e in reg (e-1)&3, col 2047-(256q+4l+e)
  const int cf  = 256 * q + 4 * lane;
  const int cs_ = 2044 - cf;
#define WROW(RR, VF, VS, FLD) { \
    unsigned short* rp = Ub + (size_t)(r0 + (RR)) * NN; \
    const unsigned uf0 = (unsigned)f2bf(VF[1].FLD) | ((unsigned)f2bf(VF[2].FLD) << 16); \
    const unsigned uf1 = (unsigned)f2bf(VF[3].FLD) | ((unsigned)f2bf(VF[0].FLD) << 16); \
    const unsigned us0 = (unsigned)f2bf(VS[2].FLD) | ((unsigned)f2bf(VS[1].FLD) << 16); \
    const unsigned us1 = (unsigned)f2bf(VS[0].FLD) | ((unsigned)f2bf(VS[3].FLD) << 16); \
    *(uint2*)(rp + cf)  = make_uint2(uf0, uf1); \
    *(uint2*)(rp + cs_) = make_uint2(us0, us1); }
  WROW(0, FFa, SSa, x) WROW(1, FFa, SSa, y)
  WROW(2, FFb, SSb, x) WROW(3, FFb, SSb, y)
}

// ---- kernel 4: C = A * B^T + bias.  A = x_bf16 [8192][2048], B = U_bf16 [2048][2048]
#define BM 128
#define BN 128
#define BK 32

__global__ __launch_bounds__(256) void gemm_kernel(
    const unsigned short* __restrict__ A, const unsigned short* __restrict__ B,
    const float* __restrict__ bias, float* __restrict__ C) {
  __shared__ unsigned short As[BM * BK];
  __shared__ unsigned short Bs[BN * BK];
  const int tid  = threadIdx.x;
  const int lane = tid & 63;
  const int wave = tid >> 6;
  const int bm = blockIdx.x, bn = blockIdx.y;
  const int wm = wave & 1, wn = wave >> 1;

  const int srow = wave * 16 + (lane >> 2);
  const int scol = (lane & 3) * 8;
  const unsigned short* Ag = A + (size_t)(bm * BM + srow) * NN + scol;
  const unsigned short* Bg = B + (size_t)(bn * BN + srow) * NN + scol;

  const int fm = lane & 15;
  const int kb = lane >> 4;

  f32x4 acc[4][4];
#pragma unroll
  for (int a_ = 0; a_ < 4; ++a_)
#pragma unroll
    for (int b_ = 0; b_ < 4; ++b_) acc[a_][b_] = (f32x4){0.f, 0.f, 0.f, 0.f};

  for (int kt = 0; kt < NN / BK; ++kt) {
    const int k0 = kt * BK;
#pragma unroll
    for (int it = 0; it < 2; ++it) {
      gload_lds16(Ag + (size_t)(it * 64) * NN + k0, &As[wave * 512 + it * 2048]);
      gload_lds16(Bg + (size_t)(it * 64) * NN + k0, &Bs[wave * 512 + it * 2048]);
    }
    __syncthreads();

    bf16x8 af[4], bfr[4];
#pragma unroll
    for (int a_ = 0; a_ < 4; ++a_)
      af[a_] = *(const bf16x8*)&As[(wm * 64 + a_ * 16 + fm) * BK + kb * 8];
#pragma unroll
    for (int b_ = 0; b_ < 4; ++b_)
      bfr[b_] = *(const bf16x8*)&Bs[(wn * 64 + b_ * 16 + fm) * BK + kb * 8];
#pragma unroll
    for (int a_ = 0; a_ < 4; ++a_)
#pragma unroll
      for (int b_ = 0; b_ < 4; ++b_)
        acc[a_][b_] = __builtin_amdgcn_mfma_f32_16x16x32_bf16(af[a_], bfr[b_], acc[a_][b_], 0, 0, 0);
    __syncthreads();
  }

  const int row_in = (lane >> 4) * 4;
#pragma unroll
  for (int a_ = 0; a_ < 4; ++a_) {
#pragma unroll
    for (int b_ = 0; b_ < 4; ++b_) {
      int gn = bn * BN + wn * 64 + b_ * 16 + fm;
      float bv = bias[gn];
#pragma unroll
      for (int v = 0; v < 4; ++v) {
        int gm = bm * BM + wm * 64 + a_ * 16 + row_in + v;
        C[(size_t)gm * NN + gn] = acc[a_][b_][v] + bv;
      }
    }
  }
}

extern "C" void kernel_launch(void* const* d_in, const int* in_sizes, int n_in,
                              void* d_out, int out_size, void* d_ws, size_t ws_size,
                              hipStream_t stream) {
  const float* x      = (const float*)d_in[0];
  const float* angles = (const float*)d_in[1];
  const float* bias   = (const float*)d_in[2];
  float* out = (float*)d_out;

  char* ws = (char*)d_ws;
  char*           cs = ws;                                 // 2052 slices * 8KB = 16,809,984 B (>=2047 real + pad)
  unsigned short* xb = (unsigned short*)(ws + 16809984);   // 33,554,432 B
  unsigned short* Ub = (unsigned short*)(ws + 50364416);   //  8,388,608 B
  // total 58,753,024 B

  prep_kernel<<<dim3(8188), dim3(256), 0, stream>>>(angles, (float2*)cs);
  cvt_kernel<<<dim3(16384), dim3(256), 0, stream>>>((const float4*)x, (ushort4*)xb,
                                                    MROWS * NN / 4);
  build_kernel<<<dim3(512), dim3(256), 0, stream>>>(cs, Ub);
  gemm_kernel<<<dim3(MROWS / BM, NN / BN), dim3(256), 0, stream>>>(xb, Ub, bias, out);
}